// Round 19
// baseline (138.446 us; speedup 1.0000x reference)
//
#include <hip/hip_runtime.h>

#define N_TOK 16384
#define D_DIM 256
#define H_DIM 1024

typedef short v8s __attribute__((ext_vector_type(8)));
typedef float v4f __attribute__((ext_vector_type(4)));

__device__ __forceinline__ unsigned short f2b(float f) {
  union { float f; unsigned int u; } v; v.f = f;
  return (unsigned short)((v.u + 0x7fffu + ((v.u >> 16) & 1u)) >> 16);
}

// GELU: erf via Abramowitz-Stegun 7.1.26 (|err| < 1.5e-7)
__device__ __forceinline__ float gelu_f(float v) {
  float av = fabsf(v);
  float z = av * 0.70710678118f;
  float t = __builtin_amdgcn_rcpf(1.0f + 0.3275911f * z);
  float poly = t * (0.254829592f + t * (-0.284496736f + t * (1.421413741f +
               t * (-1.453152027f + t * 1.061405429f))));
  float E = __expf(-z * z);
  float erf_abs = 1.0f - poly * E;
  return 0.5f * v + 0.5f * av * erf_abs;
}

// ---------------- merged prep: repack (0..639) + router (640..895) + d_out zero (896..1023) ----------------
__global__ void prep_kernel(const float* __restrict__ W1, const float* __restrict__ W2,
                            unsigned short* __restrict__ W1r, unsigned short* __restrict__ W2r,
                            const float* __restrict__ x, const float* __restrict__ rw,
                            const float* __restrict__ dirs, float* __restrict__ topk_p,
                            int* __restrict__ plist, int* __restrict__ cnt,
                            float* __restrict__ psum_part, unsigned short* __restrict__ xb,
                            float* __restrict__ out) {
  __shared__ __align__(16) char smem[16640];
  int t = threadIdx.x;
  if (blockIdx.x < 640) {
    unsigned short (*s_w)[520] = reinterpret_cast<unsigned short (*)[520]>(smem);
    int row = t >> 4, c16 = t & 15;
    if (blockIdx.x < 512) {
      int blk = blockIdx.x;            // e*64 + ht
      const float* src = W1 + (size_t)blk * 16 * 256;
#pragma unroll
      for (int it = 0; it < 4; it++) {
        int c0 = c16 * 4 + it * 64;
        float4 v = *(const float4*)(src + (size_t)row * 256 + c0);
        *(ushort4*)(&s_w[row][c0]) = make_ushort4(f2b(v.x), f2b(v.y), f2b(v.z), f2b(v.w));
      }
      __syncthreads();
      unsigned short* dst = W1r + (size_t)blk * 4096;
#pragma unroll
      for (int ph = 0; ph < 2; ph++) {
        int idx = ph * 256 + t;        // ks*64 + l
        int l = idx & 63;
        int ks = idx >> 6;
        v8s val = *(const v8s*)(&s_w[l & 15][ks * 32 + (l >> 4) * 8]);
        *(v8s*)(dst + (size_t)idx * 8) = val;
      }
    } else {
      int blk = blockIdx.x - 512;      // e*16 + dt
      const float* src = W2 + (size_t)blk * 16 * 1024;
      unsigned short* dstbase = W2r + (size_t)blk * 16384;
      for (int half = 0; half < 2; half++) {
        if (half) __syncthreads();
#pragma unroll
        for (int it = 0; it < 8; it++) {
          int c0 = c16 * 4 + it * 64;  // 0..511
          float4 v = *(const float4*)(src + (size_t)row * 1024 + half * 512 + c0);
          *(ushort4*)(&s_w[row][c0]) = make_ushort4(f2b(v.x), f2b(v.y), f2b(v.z), f2b(v.w));
        }
        __syncthreads();
#pragma unroll
        for (int ph = 0; ph < 4; ph++) {
          int idx = ph * 256 + t;      // ksl*64 + l, ksl 0..15
          int l = idx & 63;
          int ksl = idx >> 6;
          v8s val = *(const v8s*)(&s_w[l & 15][ksl * 32 + (l >> 4) * 8]);
          *(v8s*)(dstbase + ((size_t)(half * 16 + ksl) * 64 + l) * 8) = val;
        }
      }
    }
  } else if (blockIdx.x < 896) {
    // ---- router path (r13's measured-best form) ----
    int bx = blockIdx.x - 640;
    float* s_rw   = (float*)smem;                    // 768 f
    float* s_dirs = (float*)(smem + 3072);           // 24 f
    float (*s_z)[3] = (float (*)[3])(smem + 3168);   // 64x3 f
    int*   s_lc   = (int*)(smem + 3936);
    int*   s_base = (int*)(smem + 3968);
    float* s_ps   = (float*)(smem + 4000);
    int*   s_e0   = (int*)(smem + 4032);
    int*   s_e1   = (int*)(smem + 4288);
    int*   s_q0   = (int*)(smem + 4544);
    int*   s_q1   = (int*)(smem + 4800);
    float* s_w0   = (float*)(smem + 5056);
    float* s_w1   = (float*)(smem + 5312);
    for (int i = t; i < 768; i += 256) s_rw[i] = rw[i];
    if (t < 24) s_dirs[t] = dirs[t];
    if (t < 8) { s_lc[t] = 0; s_ps[t] = 0.f; }
    __syncthreads();
    int wv = t >> 6, ln = t & 63;
    float4 r0 = ((const float4*)s_rw)[ln];
    float4 r1 = ((const float4*)(s_rw + 256))[ln];
    float4 r2 = ((const float4*)(s_rw + 512))[ln];

    for (int tt = 0; tt < 16; tt++) {
      int n = bx * 64 + wv * 16 + tt;
      float4 xv = ((const float4*)(x + (size_t)n * D_DIM))[ln];
      *(ushort4*)(xb + (size_t)n * 256 + ln * 4) =
          make_ushort4(f2b(xv.x), f2b(xv.y), f2b(xv.z), f2b(xv.w));
      float d0 = xv.x*r0.x + xv.y*r0.y + xv.z*r0.z + xv.w*r0.w;
      float d1 = xv.x*r1.x + xv.y*r1.y + xv.z*r1.z + xv.w*r1.w;
      float d2 = xv.x*r2.x + xv.y*r2.y + xv.z*r2.z + xv.w*r2.w;
#pragma unroll
      for (int off = 32; off > 0; off >>= 1) {
        d0 += __shfl_xor(d0, off);
        d1 += __shfl_xor(d1, off);
        d2 += __shfl_xor(d2, off);
      }
      if (ln == 0) {
        int slot = wv * 16 + tt;
        s_z[slot][0] = d0; s_z[slot][1] = d1; s_z[slot][2] = d2;
      }
    }
    __syncthreads();
    if (ln < 16) {
      int slot = wv * 16 + ln;
      float z0 = s_z[slot][0], z1 = s_z[slot][1], z2 = s_z[slot][2];
      float p[8]; float mx = -1e30f;
#pragma unroll
      for (int e = 0; e < 8; e++) {
        p[e] = z0*s_dirs[e*3] + z1*s_dirs[e*3+1] + z2*s_dirs[e*3+2];
        mx = fmaxf(mx, p[e]);
      }
      float s = 0.f;
#pragma unroll
      for (int e = 0; e < 8; e++) { p[e] = expf(p[e] - mx); s += p[e]; }
      float inv = 1.f / s;
#pragma unroll
      for (int e = 0; e < 8; e++) { p[e] *= inv; atomicAdd(&s_ps[e], p[e]); }
      int i0 = 0;
#pragma unroll
      for (int e = 1; e < 8; e++) if (p[e] > p[i0]) i0 = e;
      int i1 = (i0 == 0) ? 1 : 0;
#pragma unroll
      for (int e = 0; e < 8; e++) if (e != i0 && p[e] > p[i1]) i1 = e;
      float den = p[i0] + p[i1] + 1e-8f;
      s_e0[slot] = i0; s_e1[slot] = i1;
      s_w0[slot] = p[i0] / den; s_w1[slot] = p[i1] / den;
      s_q0[slot] = atomicAdd(&s_lc[i0], 1);
      s_q1[slot] = atomicAdd(&s_lc[i1], 1);
    }
    __syncthreads();
    if (t < 8) {
      s_base[t] = atomicAdd(&cnt[t], s_lc[t]);
      psum_part[bx * 8 + t] = s_ps[t];
    }
    __syncthreads();
    if (t < 64) {
      int n = bx * 64 + t;
      int e0 = s_e0[t], e1 = s_e1[t];
      plist[e0 * N_TOK + s_base[e0] + s_q0[t]] = n * 2;
      plist[e1 * N_TOK + s_base[e1] + s_q1[t]] = n * 2 + 1;
      topk_p[n * 2]     = s_w0[t];
      topk_p[n * 2 + 1] = s_w1[t];
    }
  } else {
    // ---- d_out zeroing path: 128 blocks cover N*D floats (+1 aux slot) ----
    int zb = blockIdx.x - 896;
    float4 z4 = make_float4(0.f, 0.f, 0.f, 0.f);
    float4* o4 = (float4*)out;
    for (int idx = zb * 256 + t; idx < (N_TOK * D_DIM / 4); idx += 128 * 256)
      o4[idx] = z4;
    if (zb == 0 && t == 0) out[(size_t)N_TOK * D_DIM] = 0.f;
  }
}

// ---------------- fused grouped FFN + aux (block 1032) ----------------
// ffn body = r13's banked config (92.3us) + ONE new mechanism: cross-barrier REGISTER
// prefetch of next chunk's n=0 W1 fragments (8 v8s = 32 VGPR). Unlike global_load_lds
// (m131 null: barrier drains vmcnt), VGPR-dest loads stay in flight across s_barrier;
// the waitcnt lands at next chunk's first MFMA, hiding ~400cyc L2 latency under
// barrier+GELU+barrier+stage2. Budget ~96-108 VGPR < 128 cap at (256,4) -> no spill.
__launch_bounds__(256, 4)
__global__ void ffn_kernel(const unsigned short* __restrict__ xb,
                           const unsigned short* __restrict__ W1r,
                           const unsigned short* __restrict__ W2r,
                           const float* __restrict__ topk_p,
                           const int* __restrict__ plist,
                           const int* __restrict__ cnt,
                           const float* __restrict__ psum_part,
                           float* __restrict__ out) {
  __shared__ __align__(16) unsigned short Xs[32 * 256];  // 16 KB, swizzled
  __shared__ __align__(16) unsigned short Ps[32 * 128];  // 8 KB, swizzled
  __shared__ int   s_tok[32];
  __shared__ float s_pw[32];

  int b0 = blockIdx.x;
  if (b0 == 1032) {
    // ---- aux block: reduce 256x8 psum partials ----
    __shared__ float s_part[32][8];
    int t = threadIdx.x;
    int e8 = t & 7, g = t >> 3;   // 32 groups x 8 experts
    float v = 0.f;
    for (int b = g; b < 256; b += 32) v += psum_part[b * 8 + e8];
    s_part[g][e8] = v;
    __syncthreads();
    if (t < 8) {
      float s = 0.f;
#pragma unroll
      for (int gg = 0; gg < 32; gg++) s += s_part[gg][t];
      s_part[0][t] = s;
    }
    __syncthreads();
    if (t == 0) {
      float s = 0.f;
#pragma unroll
      for (int e = 0; e < 8; e++) {
        float d = s_part[0][e] * (1.f / (float)N_TOK) - 0.125f;
        s += d * d;
      }
      out[(size_t)N_TOK * D_DIM] = 0.01f * (s * 0.125f);
    }
    return;
  }

  // bijective XCD swizzle over the 1032 ffn blocks: 1032 = 8 * 129
  int bid = (b0 & 7) * 129 + (b0 >> 3);

  int e = -1, ti = 0, t0 = 0;
#pragma unroll
  for (int ee = 0; ee < 8; ee++) {
    int tiles = (cnt[ee] + 31) >> 5;
    if (e < 0 && bid < t0 + tiles) { e = ee; ti = bid - t0; }
    t0 += tiles;
  }
  if (e < 0) return;
  int tid = threadIdx.x;
  int ce = cnt[e];
  if (tid < 32) {
    int i = ti * 32 + tid;
    int tok = -1; float pw = 0.f;
    if (i < ce) {
      int pid = plist[e * N_TOK + i];
      tok = pid >> 1;
      pw = topk_p[pid];
    }
    s_tok[tid] = tok; s_pw[tid] = pw;
  }
  __syncthreads();

  // X tile -> LDS (bf16 already), XOR-swizzled rows (32 rows x 256 cols)
  {
    int r = tid >> 3, q = tid & 7;
    int tok = s_tok[r];
    const unsigned short* xrow = xb + (size_t)(tok < 0 ? 0 : tok) * 256;
#pragma unroll
    for (int it = 0; it < 4; it++) {
      int c0 = q * 32 + it * 8;
      v8s u;
      if (tok >= 0) u = *(const v8s*)(xrow + c0);
      else          u = (v8s){0, 0, 0, 0, 0, 0, 0, 0};
      int addr = r * 512 + ((c0 * 2) ^ ((r & 7) << 4));
      *reinterpret_cast<v8s*>(reinterpret_cast<char*>(Xs) + addr) = u;
    }
  }
  __syncthreads();

  int w = tid >> 6, l = tid & 63;
  int l15 = l & 15, lg = l >> 4;
  int l8 = l * 8;
  v4f zero4 = {0.f, 0.f, 0.f, 0.f};
  v4f acc2[2][4];
#pragma unroll
  for (int m = 0; m < 2; m++)
#pragma unroll
    for (int n = 0; n < 4; n++) acc2[m][n] = zero4;

  const unsigned short* W1e = W1r + (size_t)e * 262144;  // 64 ht * 8 ks * 512
  const unsigned short* W2e = W2r + (size_t)e * 262144;  // 16 dt * 32 ks * 512

  // prologue prefetch: ch=0, n=0 fragments (ks 0..7) -> 32 VGPR
  v8s pre[8];
#pragma unroll
  for (int ks = 0; ks < 8; ks++)
    pre[ks] = *reinterpret_cast<const v8s*>(
        W1e + ((size_t)(w * 2) * 8 + ks) * 512 + l8);

  for (int ch = 0; ch < 8; ch++) {
    v4f acc1[2][2];
#pragma unroll
    for (int m = 0; m < 2; m++)
#pragma unroll
      for (int n = 0; n < 2; n++) acc1[m][n] = zero4;

#pragma unroll
    for (int ks = 0; ks < 8; ks++) {
      v8s a[2];
      int kb = ks * 64 + lg * 16;
#pragma unroll
      for (int m = 0; m < 2; m++) {
        int row = m * 16 + l15;
        a[m] = *reinterpret_cast<const v8s*>(
            reinterpret_cast<const char*>(Xs) + row * 512 + (kb ^ ((row & 7) << 4)));
      }
      v8s b0 = pre[ks];                                     // n=0: prefetched
      v8s b1v = *reinterpret_cast<const v8s*>(              // n=1: inline load
          W1e + ((size_t)(ch * 8 + w * 2 + 1) * 8 + ks) * 512 + l8);
#pragma unroll
      for (int m = 0; m < 2; m++) {
        acc1[m][0] = __builtin_amdgcn_mfma_f32_16x16x32_bf16(a[m], b0,  acc1[m][0], 0, 0, 0);
        acc1[m][1] = __builtin_amdgcn_mfma_f32_16x16x32_bf16(a[m], b1v, acc1[m][1], 0, 0, 0);
      }
    }

    // issue next chunk's n=0 prefetch BEFORE the barriers: latency hides under
    // barrier + GELU + barrier + stage2 (~1500 cyc)
    if (ch < 7) {
#pragma unroll
      for (int ks = 0; ks < 8; ks++)
        pre[ks] = *reinterpret_cast<const v8s*>(
            W1e + ((size_t)((ch + 1) * 8 + w * 2) * 8 + ks) * 512 + l8);
    }

    __syncthreads();  // prior stage2 reads of Ps complete
    // GELU -> Ps (bf16, swizzled)
#pragma unroll
    for (int m = 0; m < 2; m++)
#pragma unroll
      for (int n = 0; n < 2; n++)
#pragma unroll
        for (int i = 0; i < 4; i++) {
          int row = m * 16 + lg * 4 + i;
          int col = w * 32 + n * 16 + l15;
          float g = gelu_f(acc1[m][n][i]);
          int addr = row * 256 + ((col * 2) ^ ((row & 7) << 4));
          *reinterpret_cast<unsigned short*>(reinterpret_cast<char*>(Ps) + addr) = f2b(g);
        }
    __syncthreads();

    // stage 2: out(32x256) += P(32x128) @ W2_chunk^T
#pragma unroll
    for (int ks = 0; ks < 4; ks++) {
      v8s a[2];
      int kb = ks * 64 + lg * 16;
#pragma unroll
      for (int m = 0; m < 2; m++) {
        int row = m * 16 + l15;
        a[m] = *reinterpret_cast<const v8s*>(
            reinterpret_cast<const char*>(Ps) + row * 256 + (kb ^ ((row & 7) << 4)));
      }
      v8s b[4];
#pragma unroll
      for (int n = 0; n < 4; n++) {
        b[n] = *reinterpret_cast<const v8s*>(
            W2e + ((size_t)(w * 4 + n) * 32 + ch * 4 + ks) * 512 + l8);
      }
#pragma unroll
      for (int m = 0; m < 2; m++)
#pragma unroll
        for (int n = 0; n < 4; n++)
          acc2[m][n] = __builtin_amdgcn_mfma_f32_16x16x32_bf16(a[m], b[n], acc2[m][n], 0, 0, 0);
    }
  }

  // epilogue: scale by gate prob, atomic-accumulate (exactly 2 adds per out elem)
#pragma unroll
  for (int m = 0; m < 2; m++)
#pragma unroll
    for (int i = 0; i < 4; i++) {
      int row = m * 16 + lg * 4 + i;
      int tok = s_tok[row];
      if (tok < 0) continue;
      float pw = s_pw[row];
#pragma unroll
      for (int n = 0; n < 4; n++) {
        int col = w * 64 + n * 16 + l15;
        atomicAdd(out + (size_t)tok * D_DIM + col, acc2[m][n][i] * pw);
      }
    }
}

extern "C" void kernel_launch(void* const* d_in, const int* in_sizes, int n_in,
                              void* d_out, int out_size, void* d_ws, size_t ws_size,
                              hipStream_t stream) {
  const float* x    = (const float*)d_in[0];
  const float* W1   = (const float*)d_in[1];
  const float* W2   = (const float*)d_in[2];
  const float* rw   = (const float*)d_in[3];
  const float* dirs = (const float*)d_in[4];
  float* out = (float*)d_out;
  char* ws = (char*)d_ws;
  unsigned short* W1r = (unsigned short*)(ws);                       // 4 MB
  unsigned short* W2r = (unsigned short*)(ws + (size_t)4194304);     // 4 MB
  unsigned short* xb  = (unsigned short*)(ws + (size_t)8388608);     // 8 MB
  float* topk_p    = (float*)(ws + 16777216);   // 128 KB
  int*   plist     = (int*)(ws + 16908288);     // 512 KB
  int*   cnt       = (int*)(ws + 17432576);     // 32 B
  float* psum_part = (float*)(ws + 17432640);   // 8 KB

  hipMemsetAsync(cnt, 0, 32, stream);

  prep_kernel<<<1024, 256, 0, stream>>>(W1, W2, W1r, W2r,
                                        x, rw, dirs, topk_p, plist, cnt, psum_part, xb, out);
  ffn_kernel<<<1033, 256, 0, stream>>>(xb, W1r, W2r, topk_p, plist, cnt, psum_part, out);
}

// Round 20
// 120.777 us; speedup vs baseline: 1.1463x; 1.1463x over previous
//
#include <hip/hip_runtime.h>

#define N_TOK 16384
#define D_DIM 256
#define H_DIM 1024

typedef short v8s __attribute__((ext_vector_type(8)));
typedef float v4f __attribute__((ext_vector_type(4)));

__device__ __forceinline__ unsigned short f2b(float f) {
  union { float f; unsigned int u; } v; v.f = f;
  return (unsigned short)((v.u + 0x7fffu + ((v.u >> 16) & 1u)) >> 16);
}

// GELU: erf via Abramowitz-Stegun 7.1.26 (|err| < 1.5e-7)
__device__ __forceinline__ float gelu_f(float v) {
  float av = fabsf(v);
  float z = av * 0.70710678118f;
  float t = __builtin_amdgcn_rcpf(1.0f + 0.3275911f * z);
  float poly = t * (0.254829592f + t * (-0.284496736f + t * (1.421413741f +
               t * (-1.453152027f + t * 1.061405429f))));
  float E = __expf(-z * z);
  float erf_abs = 1.0f - poly * E;
  return 0.5f * v + 0.5f * av * erf_abs;
}

// ---------------- merged prep: repack (0..639) + router (640..895) + d_out zero (896..1023) ----------------
__global__ void prep_kernel(const float* __restrict__ W1, const float* __restrict__ W2,
                            unsigned short* __restrict__ W1r, unsigned short* __restrict__ W2r,
                            const float* __restrict__ x, const float* __restrict__ rw,
                            const float* __restrict__ dirs, float* __restrict__ topk_p,
                            int* __restrict__ plist, int* __restrict__ cnt,
                            float* __restrict__ psum_part, unsigned short* __restrict__ xb,
                            float* __restrict__ out) {
  __shared__ __align__(16) char smem[16640];
  int t = threadIdx.x;
  if (blockIdx.x < 640) {
    unsigned short (*s_w)[520] = reinterpret_cast<unsigned short (*)[520]>(smem);
    int row = t >> 4, c16 = t & 15;
    if (blockIdx.x < 512) {
      int blk = blockIdx.x;            // e*64 + ht
      const float* src = W1 + (size_t)blk * 16 * 256;
#pragma unroll
      for (int it = 0; it < 4; it++) {
        int c0 = c16 * 4 + it * 64;
        float4 v = *(const float4*)(src + (size_t)row * 256 + c0);
        *(ushort4*)(&s_w[row][c0]) = make_ushort4(f2b(v.x), f2b(v.y), f2b(v.z), f2b(v.w));
      }
      __syncthreads();
      unsigned short* dst = W1r + (size_t)blk * 4096;
#pragma unroll
      for (int ph = 0; ph < 2; ph++) {
        int idx = ph * 256 + t;        // ks*64 + l
        int l = idx & 63;
        int ks = idx >> 6;
        v8s val = *(const v8s*)(&s_w[l & 15][ks * 32 + (l >> 4) * 8]);
        *(v8s*)(dst + (size_t)idx * 8) = val;
      }
    } else {
      int blk = blockIdx.x - 512;      // e*16 + dt
      const float* src = W2 + (size_t)blk * 16 * 1024;
      unsigned short* dstbase = W2r + (size_t)blk * 16384;
      for (int half = 0; half < 2; half++) {
        if (half) __syncthreads();
#pragma unroll
        for (int it = 0; it < 8; it++) {
          int c0 = c16 * 4 + it * 64;  // 0..511
          float4 v = *(const float4*)(src + (size_t)row * 1024 + half * 512 + c0);
          *(ushort4*)(&s_w[row][c0]) = make_ushort4(f2b(v.x), f2b(v.y), f2b(v.z), f2b(v.w));
        }
        __syncthreads();
#pragma unroll
        for (int ph = 0; ph < 4; ph++) {
          int idx = ph * 256 + t;      // ksl*64 + l, ksl 0..15
          int l = idx & 63;
          int ksl = idx >> 6;
          v8s val = *(const v8s*)(&s_w[l & 15][ksl * 32 + (l >> 4) * 8]);
          *(v8s*)(dstbase + ((size_t)(half * 16 + ksl) * 64 + l) * 8) = val;
        }
      }
    }
  } else if (blockIdx.x < 896) {
    // ---- router path (r13's measured-best form) ----
    int bx = blockIdx.x - 640;
    float* s_rw   = (float*)smem;                    // 768 f
    float* s_dirs = (float*)(smem + 3072);           // 24 f
    float (*s_z)[3] = (float (*)[3])(smem + 3168);   // 64x3 f
    int*   s_lc   = (int*)(smem + 3936);
    int*   s_base = (int*)(smem + 3968);
    float* s_ps   = (float*)(smem + 4000);
    int*   s_e0   = (int*)(smem + 4032);
    int*   s_e1   = (int*)(smem + 4288);
    int*   s_q0   = (int*)(smem + 4544);
    int*   s_q1   = (int*)(smem + 4800);
    float* s_w0   = (float*)(smem + 5056);
    float* s_w1   = (float*)(smem + 5312);
    for (int i = t; i < 768; i += 256) s_rw[i] = rw[i];
    if (t < 24) s_dirs[t] = dirs[t];
    if (t < 8) { s_lc[t] = 0; s_ps[t] = 0.f; }
    __syncthreads();
    int wv = t >> 6, ln = t & 63;
    float4 r0 = ((const float4*)s_rw)[ln];
    float4 r1 = ((const float4*)(s_rw + 256))[ln];
    float4 r2 = ((const float4*)(s_rw + 512))[ln];

    for (int tt = 0; tt < 16; tt++) {
      int n = bx * 64 + wv * 16 + tt;
      float4 xv = ((const float4*)(x + (size_t)n * D_DIM))[ln];
      *(ushort4*)(xb + (size_t)n * 256 + ln * 4) =
          make_ushort4(f2b(xv.x), f2b(xv.y), f2b(xv.z), f2b(xv.w));
      float d0 = xv.x*r0.x + xv.y*r0.y + xv.z*r0.z + xv.w*r0.w;
      float d1 = xv.x*r1.x + xv.y*r1.y + xv.z*r1.z + xv.w*r1.w;
      float d2 = xv.x*r2.x + xv.y*r2.y + xv.z*r2.z + xv.w*r2.w;
#pragma unroll
      for (int off = 32; off > 0; off >>= 1) {
        d0 += __shfl_xor(d0, off);
        d1 += __shfl_xor(d1, off);
        d2 += __shfl_xor(d2, off);
      }
      if (ln == 0) {
        int slot = wv * 16 + tt;
        s_z[slot][0] = d0; s_z[slot][1] = d1; s_z[slot][2] = d2;
      }
    }
    __syncthreads();
    if (ln < 16) {
      int slot = wv * 16 + ln;
      float z0 = s_z[slot][0], z1 = s_z[slot][1], z2 = s_z[slot][2];
      float p[8]; float mx = -1e30f;
#pragma unroll
      for (int e = 0; e < 8; e++) {
        p[e] = z0*s_dirs[e*3] + z1*s_dirs[e*3+1] + z2*s_dirs[e*3+2];
        mx = fmaxf(mx, p[e]);
      }
      float s = 0.f;
#pragma unroll
      for (int e = 0; e < 8; e++) { p[e] = expf(p[e] - mx); s += p[e]; }
      float inv = 1.f / s;
#pragma unroll
      for (int e = 0; e < 8; e++) { p[e] *= inv; atomicAdd(&s_ps[e], p[e]); }
      int i0 = 0;
#pragma unroll
      for (int e = 1; e < 8; e++) if (p[e] > p[i0]) i0 = e;
      int i1 = (i0 == 0) ? 1 : 0;
#pragma unroll
      for (int e = 0; e < 8; e++) if (e != i0 && p[e] > p[i1]) i1 = e;
      float den = p[i0] + p[i1] + 1e-8f;
      s_e0[slot] = i0; s_e1[slot] = i1;
      s_w0[slot] = p[i0] / den; s_w1[slot] = p[i1] / den;
      s_q0[slot] = atomicAdd(&s_lc[i0], 1);
      s_q1[slot] = atomicAdd(&s_lc[i1], 1);
    }
    __syncthreads();
    if (t < 8) {
      s_base[t] = atomicAdd(&cnt[t], s_lc[t]);
      psum_part[bx * 8 + t] = s_ps[t];
    }
    __syncthreads();
    if (t < 64) {
      int n = bx * 64 + t;
      int e0 = s_e0[t], e1 = s_e1[t];
      plist[e0 * N_TOK + s_base[e0] + s_q0[t]] = n * 2;
      plist[e1 * N_TOK + s_base[e1] + s_q1[t]] = n * 2 + 1;
      topk_p[n * 2]     = s_w0[t];
      topk_p[n * 2 + 1] = s_w1[t];
    }
  } else {
    // ---- d_out zeroing path: 128 blocks cover N*D floats (+1 aux slot) ----
    int zb = blockIdx.x - 896;
    float4 z4 = make_float4(0.f, 0.f, 0.f, 0.f);
    float4* o4 = (float4*)out;
    for (int idx = zb * 256 + t; idx < (N_TOK * D_DIM / 4); idx += 128 * 256)
      o4[idx] = z4;
    if (zb == 0 && t == 0) out[(size_t)N_TOK * D_DIM] = 0.f;
  }
}

// ---------------- fused grouped FFN + aux (block 1032): M=32, single Ps, 2 barriers/chunk ----------------
// ffn body EXACT r13/r17 banked config (measured 92.3-93.4us, VGPR 64, LDS 25-26KB, occ 29%).
// Ten structural probes all null/negative: barriers (r5/r10), occ 14-35% (r4/r15), Xa-hoist (r9),
// M=64 (r11/r12), H-split (r15), router-ILP (r16), cross-barrier reg-prefetch (r19: compiler
// pins 64 VGPR under (256,4) and spills any added cross-barrier register lifetime to scratch,
// +12MB WRITE). This is the final banked optimum.
__launch_bounds__(256, 4)
__global__ void ffn_kernel(const unsigned short* __restrict__ xb,
                           const unsigned short* __restrict__ W1r,
                           const unsigned short* __restrict__ W2r,
                           const float* __restrict__ topk_p,
                           const int* __restrict__ plist,
                           const int* __restrict__ cnt,
                           const float* __restrict__ psum_part,
                           float* __restrict__ out) {
  __shared__ __align__(16) unsigned short Xs[32 * 256];  // 16 KB, swizzled
  __shared__ __align__(16) unsigned short Ps[32 * 128];  // 8 KB, swizzled
  __shared__ int   s_tok[32];
  __shared__ float s_pw[32];

  int b0 = blockIdx.x;
  if (b0 == 1032) {
    // ---- aux block: reduce 256x8 psum partials ----
    __shared__ float s_part[32][8];
    int t = threadIdx.x;
    int e8 = t & 7, g = t >> 3;   // 32 groups x 8 experts
    float v = 0.f;
    for (int b = g; b < 256; b += 32) v += psum_part[b * 8 + e8];
    s_part[g][e8] = v;
    __syncthreads();
    if (t < 8) {
      float s = 0.f;
#pragma unroll
      for (int gg = 0; gg < 32; gg++) s += s_part[gg][t];
      s_part[0][t] = s;
    }
    __syncthreads();
    if (t == 0) {
      float s = 0.f;
#pragma unroll
      for (int e = 0; e < 8; e++) {
        float d = s_part[0][e] * (1.f / (float)N_TOK) - 0.125f;
        s += d * d;
      }
      out[(size_t)N_TOK * D_DIM] = 0.01f * (s * 0.125f);
    }
    return;
  }

  // bijective XCD swizzle over the 1032 ffn blocks: 1032 = 8 * 129
  int bid = (b0 & 7) * 129 + (b0 >> 3);

  int e = -1, ti = 0, t0 = 0;
#pragma unroll
  for (int ee = 0; ee < 8; ee++) {
    int tiles = (cnt[ee] + 31) >> 5;
    if (e < 0 && bid < t0 + tiles) { e = ee; ti = bid - t0; }
    t0 += tiles;
  }
  if (e < 0) return;
  int tid = threadIdx.x;
  int ce = cnt[e];
  if (tid < 32) {
    int i = ti * 32 + tid;
    int tok = -1; float pw = 0.f;
    if (i < ce) {
      int pid = plist[e * N_TOK + i];
      tok = pid >> 1;
      pw = topk_p[pid];
    }
    s_tok[tid] = tok; s_pw[tid] = pw;
  }
  __syncthreads();

  // X tile -> LDS (bf16 already), XOR-swizzled rows (32 rows x 256 cols)
  {
    int r = tid >> 3, q = tid & 7;
    int tok = s_tok[r];
    const unsigned short* xrow = xb + (size_t)(tok < 0 ? 0 : tok) * 256;
#pragma unroll
    for (int it = 0; it < 4; it++) {
      int c0 = q * 32 + it * 8;
      v8s u;
      if (tok >= 0) u = *(const v8s*)(xrow + c0);
      else          u = (v8s){0, 0, 0, 0, 0, 0, 0, 0};
      int addr = r * 512 + ((c0 * 2) ^ ((r & 7) << 4));
      *reinterpret_cast<v8s*>(reinterpret_cast<char*>(Xs) + addr) = u;
    }
  }
  __syncthreads();

  int w = tid >> 6, l = tid & 63;
  int l15 = l & 15, lg = l >> 4;
  int l8 = l * 8;
  v4f zero4 = {0.f, 0.f, 0.f, 0.f};
  v4f acc2[2][4];
#pragma unroll
  for (int m = 0; m < 2; m++)
#pragma unroll
    for (int n = 0; n < 4; n++) acc2[m][n] = zero4;

  const unsigned short* W1e = W1r + (size_t)e * 262144;  // 64 ht * 8 ks * 512
  const unsigned short* W2e = W2r + (size_t)e * 262144;  // 16 dt * 32 ks * 512

  for (int ch = 0; ch < 8; ch++) {
    v4f acc1[2][2];
#pragma unroll
    for (int m = 0; m < 2; m++)
#pragma unroll
      for (int n = 0; n < 2; n++) acc1[m][n] = zero4;

#pragma unroll
    for (int ks = 0; ks < 8; ks++) {
      v8s a[2];
      int kb = ks * 64 + lg * 16;
#pragma unroll
      for (int m = 0; m < 2; m++) {
        int row = m * 16 + l15;
        a[m] = *reinterpret_cast<const v8s*>(
            reinterpret_cast<const char*>(Xs) + row * 512 + (kb ^ ((row & 7) << 4)));
      }
      v8s b[2];
#pragma unroll
      for (int n = 0; n < 2; n++) {
        b[n] = *reinterpret_cast<const v8s*>(
            W1e + ((size_t)(ch * 8 + w * 2 + n) * 8 + ks) * 512 + l8);
      }
#pragma unroll
      for (int m = 0; m < 2; m++)
#pragma unroll
        for (int n = 0; n < 2; n++)
          acc1[m][n] = __builtin_amdgcn_mfma_f32_16x16x32_bf16(a[m], b[n], acc1[m][n], 0, 0, 0);
    }

    __syncthreads();  // prior stage2 reads of Ps complete
    // GELU -> Ps (bf16, swizzled)
#pragma unroll
    for (int m = 0; m < 2; m++)
#pragma unroll
      for (int n = 0; n < 2; n++)
#pragma unroll
        for (int i = 0; i < 4; i++) {
          int row = m * 16 + lg * 4 + i;
          int col = w * 32 + n * 16 + l15;
          float g = gelu_f(acc1[m][n][i]);
          int addr = row * 256 + ((col * 2) ^ ((row & 7) << 4));
          *reinterpret_cast<unsigned short*>(reinterpret_cast<char*>(Ps) + addr) = f2b(g);
        }
    __syncthreads();

    // stage 2: out(32x256) += P(32x128) @ W2_chunk^T
#pragma unroll
    for (int ks = 0; ks < 4; ks++) {
      v8s a[2];
      int kb = ks * 64 + lg * 16;
#pragma unroll
      for (int m = 0; m < 2; m++) {
        int row = m * 16 + l15;
        a[m] = *reinterpret_cast<const v8s*>(
            reinterpret_cast<const char*>(Ps) + row * 256 + (kb ^ ((row & 7) << 4)));
      }
      v8s b[4];
#pragma unroll
      for (int n = 0; n < 4; n++) {
        b[n] = *reinterpret_cast<const v8s*>(
            W2e + ((size_t)(w * 4 + n) * 32 + ch * 4 + ks) * 512 + l8);
      }
#pragma unroll
      for (int m = 0; m < 2; m++)
#pragma unroll
        for (int n = 0; n < 4; n++)
          acc2[m][n] = __builtin_amdgcn_mfma_f32_16x16x32_bf16(a[m], b[n], acc2[m][n], 0, 0, 0);
    }
  }

  // epilogue: scale by gate prob, atomic-accumulate (exactly 2 adds per out elem)
#pragma unroll
  for (int m = 0; m < 2; m++)
#pragma unroll
    for (int i = 0; i < 4; i++) {
      int row = m * 16 + lg * 4 + i;
      int tok = s_tok[row];
      if (tok < 0) continue;
      float pw = s_pw[row];
#pragma unroll
      for (int n = 0; n < 4; n++) {
        int col = w * 64 + n * 16 + l15;
        atomicAdd(out + (size_t)tok * D_DIM + col, acc2[m][n][i] * pw);
      }
    }
}

extern "C" void kernel_launch(void* const* d_in, const int* in_sizes, int n_in,
                              void* d_out, int out_size, void* d_ws, size_t ws_size,
                              hipStream_t stream) {
  const float* x    = (const float*)d_in[0];
  const float* W1   = (const float*)d_in[1];
  const float* W2   = (const float*)d_in[2];
  const float* rw   = (const float*)d_in[3];
  const float* dirs = (const float*)d_in[4];
  float* out = (float*)d_out;
  char* ws = (char*)d_ws;
  unsigned short* W1r = (unsigned short*)(ws);                       // 4 MB
  unsigned short* W2r = (unsigned short*)(ws + (size_t)4194304);     // 4 MB
  unsigned short* xb  = (unsigned short*)(ws + (size_t)8388608);     // 8 MB
  float* topk_p    = (float*)(ws + 16777216);   // 128 KB
  int*   plist     = (int*)(ws + 16908288);     // 512 KB
  int*   cnt       = (int*)(ws + 17432576);     // 32 B
  float* psum_part = (float*)(ws + 17432640);   // 8 KB

  hipMemsetAsync(cnt, 0, 32, stream);

  prep_kernel<<<1024, 256, 0, stream>>>(W1, W2, W1r, W2r,
                                        x, rw, dirs, topk_p, plist, cnt, psum_part, xb, out);
  ffn_kernel<<<1033, 256, 0, stream>>>(xb, W1r, W2r, topk_p, plist, cnt, psum_part, out);
}

// Round 21
// 115.952 us; speedup vs baseline: 1.1940x; 1.0416x over previous
//
#include <hip/hip_runtime.h>

#define N_TOK 16384
#define D_DIM 256
#define H_DIM 1024

typedef short v8s __attribute__((ext_vector_type(8)));
typedef float v4f __attribute__((ext_vector_type(4)));

__device__ __forceinline__ unsigned short f2b(float f) {
  union { float f; unsigned int u; } v; v.f = f;
  return (unsigned short)((v.u + 0x7fffu + ((v.u >> 16) & 1u)) >> 16);
}

// GELU: erf via Abramowitz-Stegun 7.1.26 (|err| < 1.5e-7)
__device__ __forceinline__ float gelu_f(float v) {
  float av = fabsf(v);
  float z = av * 0.70710678118f;
  float t = __builtin_amdgcn_rcpf(1.0f + 0.3275911f * z);
  float poly = t * (0.254829592f + t * (-0.284496736f + t * (1.421413741f +
               t * (-1.453152027f + t * 1.061405429f))));
  float E = __expf(-z * z);
  float erf_abs = 1.0f - poly * E;
  return 0.5f * v + 0.5f * av * erf_abs;
}

// ---------------- merged prep: repack (0..639) + router (640..895) + d_out zero (896..1023) ----------------
__global__ void prep_kernel(const float* __restrict__ W1, const float* __restrict__ W2,
                            unsigned short* __restrict__ W1r, unsigned short* __restrict__ W2r,
                            const float* __restrict__ x, const float* __restrict__ rw,
                            const float* __restrict__ dirs, float* __restrict__ topk_p,
                            int* __restrict__ plist, int* __restrict__ cnt,
                            float* __restrict__ psum_part, unsigned short* __restrict__ xb,
                            float* __restrict__ out) {
  __shared__ __align__(16) char smem[16640];
  int t = threadIdx.x;
  if (blockIdx.x < 640) {
    unsigned short (*s_w)[520] = reinterpret_cast<unsigned short (*)[520]>(smem);
    int row = t >> 4, c16 = t & 15;
    if (blockIdx.x < 512) {
      int blk = blockIdx.x;            // e*64 + ht
      const float* src = W1 + (size_t)blk * 16 * 256;
#pragma unroll
      for (int it = 0; it < 4; it++) {
        int c0 = c16 * 4 + it * 64;
        float4 v = *(const float4*)(src + (size_t)row * 256 + c0);
        *(ushort4*)(&s_w[row][c0]) = make_ushort4(f2b(v.x), f2b(v.y), f2b(v.z), f2b(v.w));
      }
      __syncthreads();
      unsigned short* dst = W1r + (size_t)blk * 4096;
#pragma unroll
      for (int ph = 0; ph < 2; ph++) {
        int idx = ph * 256 + t;        // ks*64 + l
        int l = idx & 63;
        int ks = idx >> 6;
        v8s val = *(const v8s*)(&s_w[l & 15][ks * 32 + (l >> 4) * 8]);
        *(v8s*)(dst + (size_t)idx * 8) = val;
      }
    } else {
      int blk = blockIdx.x - 512;      // e*16 + dt
      const float* src = W2 + (size_t)blk * 16 * 1024;
      unsigned short* dstbase = W2r + (size_t)blk * 16384;
      for (int half = 0; half < 2; half++) {
        if (half) __syncthreads();
#pragma unroll
        for (int it = 0; it < 8; it++) {
          int c0 = c16 * 4 + it * 64;  // 0..511
          float4 v = *(const float4*)(src + (size_t)row * 1024 + half * 512 + c0);
          *(ushort4*)(&s_w[row][c0]) = make_ushort4(f2b(v.x), f2b(v.y), f2b(v.z), f2b(v.w));
        }
        __syncthreads();
#pragma unroll
        for (int ph = 0; ph < 4; ph++) {
          int idx = ph * 256 + t;      // ksl*64 + l, ksl 0..15
          int l = idx & 63;
          int ksl = idx >> 6;
          v8s val = *(const v8s*)(&s_w[l & 15][ksl * 32 + (l >> 4) * 8]);
          *(v8s*)(dstbase + ((size_t)(half * 16 + ksl) * 64 + l) * 8) = val;
        }
      }
    }
  } else if (blockIdx.x < 896) {
    // ---- router path (r13's measured-best form) ----
    int bx = blockIdx.x - 640;
    float* s_rw   = (float*)smem;                    // 768 f
    float* s_dirs = (float*)(smem + 3072);           // 24 f
    float (*s_z)[3] = (float (*)[3])(smem + 3168);   // 64x3 f
    int*   s_lc   = (int*)(smem + 3936);
    int*   s_base = (int*)(smem + 3968);
    float* s_ps   = (float*)(smem + 4000);
    int*   s_e0   = (int*)(smem + 4032);
    int*   s_e1   = (int*)(smem + 4288);
    int*   s_q0   = (int*)(smem + 4544);
    int*   s_q1   = (int*)(smem + 4800);
    float* s_w0   = (float*)(smem + 5056);
    float* s_w1   = (float*)(smem + 5312);
    for (int i = t; i < 768; i += 256) s_rw[i] = rw[i];
    if (t < 24) s_dirs[t] = dirs[t];
    if (t < 8) { s_lc[t] = 0; s_ps[t] = 0.f; }
    __syncthreads();
    int wv = t >> 6, ln = t & 63;
    float4 r0 = ((const float4*)s_rw)[ln];
    float4 r1 = ((const float4*)(s_rw + 256))[ln];
    float4 r2 = ((const float4*)(s_rw + 512))[ln];

    for (int tt = 0; tt < 16; tt++) {
      int n = bx * 64 + wv * 16 + tt;
      float4 xv = ((const float4*)(x + (size_t)n * D_DIM))[ln];
      *(ushort4*)(xb + (size_t)n * 256 + ln * 4) =
          make_ushort4(f2b(xv.x), f2b(xv.y), f2b(xv.z), f2b(xv.w));
      float d0 = xv.x*r0.x + xv.y*r0.y + xv.z*r0.z + xv.w*r0.w;
      float d1 = xv.x*r1.x + xv.y*r1.y + xv.z*r1.z + xv.w*r1.w;
      float d2 = xv.x*r2.x + xv.y*r2.y + xv.z*r2.z + xv.w*r2.w;
#pragma unroll
      for (int off = 32; off > 0; off >>= 1) {
        d0 += __shfl_xor(d0, off);
        d1 += __shfl_xor(d1, off);
        d2 += __shfl_xor(d2, off);
      }
      if (ln == 0) {
        int slot = wv * 16 + tt;
        s_z[slot][0] = d0; s_z[slot][1] = d1; s_z[slot][2] = d2;
      }
    }
    __syncthreads();
    if (ln < 16) {
      int slot = wv * 16 + ln;
      float z0 = s_z[slot][0], z1 = s_z[slot][1], z2 = s_z[slot][2];
      float p[8]; float mx = -1e30f;
#pragma unroll
      for (int e = 0; e < 8; e++) {
        p[e] = z0*s_dirs[e*3] + z1*s_dirs[e*3+1] + z2*s_dirs[e*3+2];
        mx = fmaxf(mx, p[e]);
      }
      float s = 0.f;
#pragma unroll
      for (int e = 0; e < 8; e++) { p[e] = expf(p[e] - mx); s += p[e]; }
      float inv = 1.f / s;
#pragma unroll
      for (int e = 0; e < 8; e++) { p[e] *= inv; atomicAdd(&s_ps[e], p[e]); }
      int i0 = 0;
#pragma unroll
      for (int e = 1; e < 8; e++) if (p[e] > p[i0]) i0 = e;
      int i1 = (i0 == 0) ? 1 : 0;
#pragma unroll
      for (int e = 0; e < 8; e++) if (e != i0 && p[e] > p[i1]) i1 = e;
      float den = p[i0] + p[i1] + 1e-8f;
      s_e0[slot] = i0; s_e1[slot] = i1;
      s_w0[slot] = p[i0] / den; s_w1[slot] = p[i1] / den;
      s_q0[slot] = atomicAdd(&s_lc[i0], 1);
      s_q1[slot] = atomicAdd(&s_lc[i1], 1);
    }
    __syncthreads();
    if (t < 8) {
      s_base[t] = atomicAdd(&cnt[t], s_lc[t]);
      psum_part[bx * 8 + t] = s_ps[t];
    }
    __syncthreads();
    if (t < 64) {
      int n = bx * 64 + t;
      int e0 = s_e0[t], e1 = s_e1[t];
      plist[e0 * N_TOK + s_base[e0] + s_q0[t]] = n * 2;
      plist[e1 * N_TOK + s_base[e1] + s_q1[t]] = n * 2 + 1;
      topk_p[n * 2]     = s_w0[t];
      topk_p[n * 2 + 1] = s_w1[t];
    }
  } else {
    // ---- d_out zeroing path: 128 blocks cover N*D floats (+1 aux slot) ----
    int zb = blockIdx.x - 896;
    float4 z4 = make_float4(0.f, 0.f, 0.f, 0.f);
    float4* o4 = (float4*)out;
    for (int idx = zb * 256 + t; idx < (N_TOK * D_DIM / 4); idx += 128 * 256)
      o4[idx] = z4;
    if (zb == 0 && t == 0) out[(size_t)N_TOK * D_DIM] = 0.f;
  }
}

// ---------------- fused grouped FFN + aux (block 1032): M=32, single Ps, 2 barriers/chunk ----------------
// ffn body = r17/r20 banked config (92.3-93.4us) + T5 s_setprio(1) around the two MFMA
// clusters. Mechanism: ~3.7 independent blocks/CU at different phases (attn-like, m191 +4-7%),
// not single-block lockstep (m190 null). Zero register/LDS cost -> spill tripwire can't fire.
__launch_bounds__(256, 4)
__global__ void ffn_kernel(const unsigned short* __restrict__ xb,
                           const unsigned short* __restrict__ W1r,
                           const unsigned short* __restrict__ W2r,
                           const float* __restrict__ topk_p,
                           const int* __restrict__ plist,
                           const int* __restrict__ cnt,
                           const float* __restrict__ psum_part,
                           float* __restrict__ out) {
  __shared__ __align__(16) unsigned short Xs[32 * 256];  // 16 KB, swizzled
  __shared__ __align__(16) unsigned short Ps[32 * 128];  // 8 KB, swizzled
  __shared__ int   s_tok[32];
  __shared__ float s_pw[32];

  int b0 = blockIdx.x;
  if (b0 == 1032) {
    // ---- aux block: reduce 256x8 psum partials ----
    __shared__ float s_part[32][8];
    int t = threadIdx.x;
    int e8 = t & 7, g = t >> 3;   // 32 groups x 8 experts
    float v = 0.f;
    for (int b = g; b < 256; b += 32) v += psum_part[b * 8 + e8];
    s_part[g][e8] = v;
    __syncthreads();
    if (t < 8) {
      float s = 0.f;
#pragma unroll
      for (int gg = 0; gg < 32; gg++) s += s_part[gg][t];
      s_part[0][t] = s;
    }
    __syncthreads();
    if (t == 0) {
      float s = 0.f;
#pragma unroll
      for (int e = 0; e < 8; e++) {
        float d = s_part[0][e] * (1.f / (float)N_TOK) - 0.125f;
        s += d * d;
      }
      out[(size_t)N_TOK * D_DIM] = 0.01f * (s * 0.125f);
    }
    return;
  }

  // bijective XCD swizzle over the 1032 ffn blocks: 1032 = 8 * 129
  int bid = (b0 & 7) * 129 + (b0 >> 3);

  int e = -1, ti = 0, t0 = 0;
#pragma unroll
  for (int ee = 0; ee < 8; ee++) {
    int tiles = (cnt[ee] + 31) >> 5;
    if (e < 0 && bid < t0 + tiles) { e = ee; ti = bid - t0; }
    t0 += tiles;
  }
  if (e < 0) return;
  int tid = threadIdx.x;
  int ce = cnt[e];
  if (tid < 32) {
    int i = ti * 32 + tid;
    int tok = -1; float pw = 0.f;
    if (i < ce) {
      int pid = plist[e * N_TOK + i];
      tok = pid >> 1;
      pw = topk_p[pid];
    }
    s_tok[tid] = tok; s_pw[tid] = pw;
  }
  __syncthreads();

  // X tile -> LDS (bf16 already), XOR-swizzled rows (32 rows x 256 cols)
  {
    int r = tid >> 3, q = tid & 7;
    int tok = s_tok[r];
    const unsigned short* xrow = xb + (size_t)(tok < 0 ? 0 : tok) * 256;
#pragma unroll
    for (int it = 0; it < 4; it++) {
      int c0 = q * 32 + it * 8;
      v8s u;
      if (tok >= 0) u = *(const v8s*)(xrow + c0);
      else          u = (v8s){0, 0, 0, 0, 0, 0, 0, 0};
      int addr = r * 512 + ((c0 * 2) ^ ((r & 7) << 4));
      *reinterpret_cast<v8s*>(reinterpret_cast<char*>(Xs) + addr) = u;
    }
  }
  __syncthreads();

  int w = tid >> 6, l = tid & 63;
  int l15 = l & 15, lg = l >> 4;
  int l8 = l * 8;
  v4f zero4 = {0.f, 0.f, 0.f, 0.f};
  v4f acc2[2][4];
#pragma unroll
  for (int m = 0; m < 2; m++)
#pragma unroll
    for (int n = 0; n < 4; n++) acc2[m][n] = zero4;

  const unsigned short* W1e = W1r + (size_t)e * 262144;  // 64 ht * 8 ks * 512
  const unsigned short* W2e = W2r + (size_t)e * 262144;  // 16 dt * 32 ks * 512

  for (int ch = 0; ch < 8; ch++) {
    v4f acc1[2][2];
#pragma unroll
    for (int m = 0; m < 2; m++)
#pragma unroll
      for (int n = 0; n < 2; n++) acc1[m][n] = zero4;

    __builtin_amdgcn_s_setprio(1);
#pragma unroll
    for (int ks = 0; ks < 8; ks++) {
      v8s a[2];
      int kb = ks * 64 + lg * 16;
#pragma unroll
      for (int m = 0; m < 2; m++) {
        int row = m * 16 + l15;
        a[m] = *reinterpret_cast<const v8s*>(
            reinterpret_cast<const char*>(Xs) + row * 512 + (kb ^ ((row & 7) << 4)));
      }
      v8s b[2];
#pragma unroll
      for (int n = 0; n < 2; n++) {
        b[n] = *reinterpret_cast<const v8s*>(
            W1e + ((size_t)(ch * 8 + w * 2 + n) * 8 + ks) * 512 + l8);
      }
#pragma unroll
      for (int m = 0; m < 2; m++)
#pragma unroll
        for (int n = 0; n < 2; n++)
          acc1[m][n] = __builtin_amdgcn_mfma_f32_16x16x32_bf16(a[m], b[n], acc1[m][n], 0, 0, 0);
    }
    __builtin_amdgcn_s_setprio(0);

    __syncthreads();  // prior stage2 reads of Ps complete
    // GELU -> Ps (bf16, swizzled)
#pragma unroll
    for (int m = 0; m < 2; m++)
#pragma unroll
      for (int n = 0; n < 2; n++)
#pragma unroll
        for (int i = 0; i < 4; i++) {
          int row = m * 16 + lg * 4 + i;
          int col = w * 32 + n * 16 + l15;
          float g = gelu_f(acc1[m][n][i]);
          int addr = row * 256 + ((col * 2) ^ ((row & 7) << 4));
          *reinterpret_cast<unsigned short*>(reinterpret_cast<char*>(Ps) + addr) = f2b(g);
        }
    __syncthreads();

    // stage 2: out(32x256) += P(32x128) @ W2_chunk^T
    __builtin_amdgcn_s_setprio(1);
#pragma unroll
    for (int ks = 0; ks < 4; ks++) {
      v8s a[2];
      int kb = ks * 64 + lg * 16;
#pragma unroll
      for (int m = 0; m < 2; m++) {
        int row = m * 16 + l15;
        a[m] = *reinterpret_cast<const v8s*>(
            reinterpret_cast<const char*>(Ps) + row * 256 + (kb ^ ((row & 7) << 4)));
      }
      v8s b[4];
#pragma unroll
      for (int n = 0; n < 4; n++) {
        b[n] = *reinterpret_cast<const v8s*>(
            W2e + ((size_t)(w * 4 + n) * 32 + ch * 4 + ks) * 512 + l8);
      }
#pragma unroll
      for (int m = 0; m < 2; m++)
#pragma unroll
        for (int n = 0; n < 4; n++)
          acc2[m][n] = __builtin_amdgcn_mfma_f32_16x16x32_bf16(a[m], b[n], acc2[m][n], 0, 0, 0);
    }
    __builtin_amdgcn_s_setprio(0);
  }

  // epilogue: scale by gate prob, atomic-accumulate (exactly 2 adds per out elem)
#pragma unroll
  for (int m = 0; m < 2; m++)
#pragma unroll
    for (int i = 0; i < 4; i++) {
      int row = m * 16 + lg * 4 + i;
      int tok = s_tok[row];
      if (tok < 0) continue;
      float pw = s_pw[row];
#pragma unroll
      for (int n = 0; n < 4; n++) {
        int col = w * 64 + n * 16 + l15;
        atomicAdd(out + (size_t)tok * D_DIM + col, acc2[m][n][i] * pw);
      }
    }
}

extern "C" void kernel_launch(void* const* d_in, const int* in_sizes, int n_in,
                              void* d_out, int out_size, void* d_ws, size_t ws_size,
                              hipStream_t stream) {
  const float* x    = (const float*)d_in[0];
  const float* W1   = (const float*)d_in[1];
  const float* W2   = (const float*)d_in[2];
  const float* rw   = (const float*)d_in[3];
  const float* dirs = (const float*)d_in[4];
  float* out = (float*)d_out;
  char* ws = (char*)d_ws;
  unsigned short* W1r = (unsigned short*)(ws);                       // 4 MB
  unsigned short* W2r = (unsigned short*)(ws + (size_t)4194304);     // 4 MB
  unsigned short* xb  = (unsigned short*)(ws + (size_t)8388608);     // 8 MB
  float* topk_p    = (float*)(ws + 16777216);   // 128 KB
  int*   plist     = (int*)(ws + 16908288);     // 512 KB
  int*   cnt       = (int*)(ws + 17432576);     // 32 B
  float* psum_part = (float*)(ws + 17432640);   // 8 KB

  hipMemsetAsync(cnt, 0, 32, stream);

  prep_kernel<<<1024, 256, 0, stream>>>(W1, W2, W1r, W2r,
                                        x, rw, dirs, topk_p, plist, cnt, psum_part, xb, out);
  ffn_kernel<<<1033, 256, 0, stream>>>(xb, W1r, W2r, topk_p, plist, cnt, psum_part, out);
}